// Round 1
// baseline (508.154 us; speedup 1.0000x reference)
//
#include <hip/hip_runtime.h>
#include <hip/hip_fp16.h>
#include <stdint.h>

// Correlation layer (FlowNet-style), D=4, S1=S2=1.
// x1,x2: (4,128,256,256) f32  ->  out: (4,81,256,256) f32
// out[n, dy*9+dx, y, x] = (1/128) sum_c x1[n,c,y,x] * x2[n,c,y+dy-4,x+dx-4] (zero pad)

#define NN   4
#define CC   128
#define HH   256
#define WW   256
#define DD   4
#define KD   9          // 2*DD+1
#define NK   81         // KD*KD
#define TILE 16
#define CH   8          // channels staged per LDS chunk (even, divides CC)
#define XW   24         // TILE + 2*DD

typedef _Float16 half2v __attribute__((ext_vector_type(2)));

__global__ __launch_bounds__(256, 4)
void corr_dot2_kernel(const float* __restrict__ x1,
                      const float* __restrict__ x2,
                      float* __restrict__ out)
{
    // x2 halo tile and x1 tile, fp16 channel-pairs packed in u32
    __shared__ uint32_t s_x2[CH/2][XW][XW];
    __shared__ uint32_t s_x1[CH/2][TILE][TILE];

    const int tid = threadIdx.x;
    const int tx  = tid & 15;
    const int ty  = tid >> 4;
    const int x0  = blockIdx.x * TILE;
    const int y0  = blockIdx.y * TILE;
    const int n   = blockIdx.z;

    const float* X1 = x1 + (size_t)n * CC * HH * WW;
    const float* X2 = x2 + (size_t)n * CC * HH * WW;

    float acc[NK];
#pragma unroll
    for (int k = 0; k < NK; ++k) acc[k] = 0.f;

    for (int c0 = 0; c0 < CC; c0 += CH) {
        __syncthreads();   // previous chunk's readers done before overwrite

        // ---- stage x2 halo tile: rows y0-4..y0+19, cols x0-4..x0+19
#pragma unroll
        for (int i = 0; i < (CH/2)*XW*XW/256; ++i) {      // 9 iters exactly
            int idx = tid + i * 256;
            int col = idx % XW;
            int row = (idx / XW) % XW;
            int j   = idx / (XW*XW);
            int gy  = y0 - DD + row;
            int gx  = x0 - DD + col;
            float f0 = 0.f, f1 = 0.f;
            if ((unsigned)gy < HH && (unsigned)gx < WW) {
                const float* p = X2 + ((size_t)(c0 + 2*j) * HH + gy) * WW + gx;
                f0 = p[0];
                f1 = p[HH*WW];
            }
            half2v h; h.x = (_Float16)f0; h.y = (_Float16)f1;
            s_x2[j][row][col] = __builtin_bit_cast(uint32_t, h);
        }
        // ---- stage x1 tile (always in-bounds)
#pragma unroll
        for (int i = 0; i < (CH/2)*TILE*TILE/256; ++i) {  // 4 iters exactly
            int idx = tid + i * 256;
            int col = idx & 15;
            int row = (idx >> 4) & 15;
            int j   = idx >> 8;
            const float* p = X1 + ((size_t)(c0 + 2*j) * HH + (y0 + row)) * WW + (x0 + col);
            half2v h; h.x = (_Float16)p[0]; h.y = (_Float16)p[HH*WW];
            s_x1[j][row][col] = __builtin_bit_cast(uint32_t, h);
        }
        __syncthreads();

        // ---- accumulate: 81 dot2 per channel-pair; x1 operand register-resident
#pragma unroll
        for (int j = 0; j < CH/2; ++j) {
            half2v a = __builtin_bit_cast(half2v, s_x1[j][ty][tx]);
#pragma unroll
            for (int dy = 0; dy < KD; ++dy) {
                const uint32_t* brow = &s_x2[j][ty + dy][tx];
#pragma unroll
                for (int dx = 0; dx < KD; ++dx) {
                    half2v b = __builtin_bit_cast(half2v, brow[dx]);
#if __has_builtin(__builtin_amdgcn_fdot2)
                    acc[dy*KD + dx] = __builtin_amdgcn_fdot2(a, b, acc[dy*KD + dx], false);
#else
                    acc[dy*KD + dx] += (float)a.x * (float)b.x + (float)a.y * (float)b.y;
#endif
                }
            }
        }
    }

    // ---- epilogue
    const int y = y0 + ty, x = x0 + tx;
    float* O = out + (size_t)n * NK * (HH*WW) + (size_t)y * WW + x;
#pragma unroll
    for (int k = 0; k < NK; ++k) {
        O[(size_t)k * (HH*WW)] = acc[k] * (1.0f / CC);
    }
}

extern "C" void kernel_launch(void* const* d_in, const int* in_sizes, int n_in,
                              void* d_out, int out_size, void* d_ws, size_t ws_size,
                              hipStream_t stream)
{
    const float* x1 = (const float*)d_in[0];
    const float* x2 = (const float*)d_in[1];
    float* out = (float*)d_out;

    dim3 grid(WW / TILE, HH / TILE, NN);   // 16 x 16 x 4 = 1024 blocks
    dim3 block(256);
    corr_dot2_kernel<<<grid, block, 0, stream>>>(x1, x2, out);
}